// Round 1
// 210.652 us; speedup vs baseline: 1.0109x; 1.0109x over previous
//
#include <hip/hip_runtime.h>
#include <stdint.h>

typedef unsigned short u16;
typedef unsigned int   u32;

typedef float  f32x4  __attribute__((ext_vector_type(4)));
typedef __bf16 bf16x8 __attribute__((ext_vector_type(8)));

template <int V> struct ic { static constexpr int value = V; };

// ---------- helpers ----------
__device__ __forceinline__ u16 f2bf(float f) {
  union { float f; u32 u; } c; c.f = f;
  u32 u = c.u + 0x7fffu + ((c.u >> 16) & 1u);   // RNE; inputs finite
  return (u16)(u >> 16);
}
__device__ __forceinline__ float bf2f(u16 h) {
  union { u32 u; float f; } c; c.u = ((u32)h) << 16;
  return c.f;
}
__device__ __forceinline__ void gll16(const void* g, void* l) {
  __builtin_amdgcn_global_load_lds(
      (const __attribute__((address_space(1))) void*)g,
      (__attribute__((address_space(3))) void*)l, 16, 0, 0);
}

// ---------- fused fp32 -> bf16 convert: x, Wi, Wo in ONE dispatch ----------
__global__ __launch_bounds__(256)
void cvt_all(const float4* __restrict__ x,  uint2* __restrict__ xb,  int n4x,
             const float4* __restrict__ wi, uint2* __restrict__ wib,
             const float4* __restrict__ wo, uint2* __restrict__ wob, int n4w) {
  int i = blockIdx.x * 256 + threadIdx.x;
  const float4* s; uint2* d; int j;
  if (i < n4x)            { s = x;  d = xb;  j = i; }
  else if (i < n4x + n4w) { s = wi; d = wib; j = i - n4x; }
  else                    { s = wo; d = wob; j = i - n4x - n4w; }
  float4 v = s[j];
  uint2 o;
  o.x = (u32)f2bf(v.x) | ((u32)f2bf(v.y) << 16);
  o.y = (u32)f2bf(v.z) | ((u32)f2bf(v.w) << 16);
  d[j] = o;
}

// ---------- bf16 NT GEMM, 256x256 tile, 8-phase counted-vmcnt schedule ----
// C[M,N] = A[M,K] * B[N,K]^T.  512 threads = 8 waves (2 m-waves x 4 n-waves),
// per-wave output 128x64 (8x4 fragments of 16x16, K-step 32).
// LDS 128 KiB: [buf2][mat2][ksub2][256 rows][32 bf16]; each half-tile
// (one ksub of A or B) is a 16 KiB LINEAR block -> global_load_lds works.
// K-tile (BK=64) = 4 phases: (m-half, ksub) in order (0,0)(0,1)(1,0)(1,1).
// Per phase: issue ONE half-tile prefetch of tile t+1 (order As0,Bs0,As1,Bs1),
// counted vmcnt (6 at P0, 4 at P1, none at P2/P3 -- never 0 in steady state),
// raw s_barrier, ds_read fragments, setprio(1) around 16 MFMA.
// Safety: the only overwrite-vs-read overlap is P0's As0 issue vs stragglers
// in previous tile's P3 reads -- disjoint ksub regions (s0 write, s1 reads).
// Swizzle: chunk position pc = q ^ ((ml>>2)&3), applied on the pre-swizzled
// GLOBAL source (g = (tid&3) ^ ((tid>>4)&3)) so LDS dest stays lane-linear;
// ds_read_b128 aliasing is 2-way max (free).
template <bool OUT_BF16>
__global__ __launch_bounds__(512, 2)
void gemm_nt_256(const u16* __restrict__ A, const u16* __restrict__ B,
                 void* __restrict__ Cout, int M, int N, int K) {
  __shared__ u16 Ls[65536];                       // 128 KiB
  const int tid  = threadIdx.x;
  const int lane = tid & 63;
  const int wave = tid >> 6;                      // 0..7
  const int wm   = wave >> 2;                     // 0..1
  const int wn   = wave & 3;                      // 0..3
  const int ml   = lane & 15;
  const int q    = lane >> 4;                     // 0..3
  const int pc   = q ^ ((ml >> 2) & 3);           // swizzled chunk position

  // ---- XCD-locality swizzle (bijection; gridDim.x == 4, gridDim.y % 8 == 0)
  const int flat = blockIdx.y * 4 + blockIdx.x;   // 0..255
  const int xcd  = flat & 7;
  const int slot = flat >> 3;                     // 0..31
  const int mt   = xcd * (gridDim.y >> 3) + (slot >> 2);
  const int nt   = slot & 3;
  const int m0   = mt * 256;
  const int n0   = nt * 256;

  // ---- staging addresses (pre-swizzled global source, linear LDS dest) ----
  const int g    = (tid & 3) ^ ((tid >> 4) & 3);  // global k-group this lane fetches
  const int srow = tid >> 2;                      // 0..127
  const u16* Ag = A + (size_t)(m0 + srow) * K + g * 8;
  const u16* Bg = B + (size_t)(n0 + srow) * K + g * 8;
  char* LsB = (char*)Ls;
  const int wb = wave * 1024;                     // wave-uniform byte base

  auto stageA = [&](int bufsel, int s, int k0) {
    char* lb = LsB + (size_t)(bufsel * 4 + s) * 16384 + wb;
    gll16(Ag + k0 + s * 32, lb);
    gll16(Ag + (size_t)128 * K + k0 + s * 32, lb + 8192);
  };
  auto stageB = [&](int bufsel, int s, int k0) {
    char* lb = LsB + (size_t)(bufsel * 4 + 2 + s) * 16384 + wb;
    gll16(Bg + k0 + s * 32, lb);
    gll16(Bg + (size_t)128 * K + k0 + s * 32, lb + 8192);
  };

  f32x4  acc[8][4] = {};
  bf16x8 bfv[2][4];                               // B frags per ksub, held across m-halves
  const int aoff = (wm * 128 + ml) * 32 + pc * 8; // u16 offset within [mat][s] block
  const int boff = (wn * 64 + ml) * 32 + pc * 8;

  auto phase = [&](auto MHc, auto Sc, auto RDBc, int buf) {
    constexpr int MH = MHc.value;
    constexpr int S  = Sc.value;
    __builtin_amdgcn_s_barrier();
    __builtin_amdgcn_sched_barrier(0);
    const u16* Ab = Ls + (size_t)(buf * 4 + S) * 8192;
    const u16* Bb = Ls + (size_t)(buf * 4 + 2 + S) * 8192;
    bf16x8 a[4];
#pragma unroll
    for (int i = 0; i < 4; ++i)
      a[i] = *reinterpret_cast<const bf16x8*>(&Ab[aoff + MH * 2048 + i * 512]);
    if constexpr (RDBc.value != 0) {
#pragma unroll
      for (int j = 0; j < 4; ++j)
        bfv[S][j] = *reinterpret_cast<const bf16x8*>(&Bb[boff + j * 512]);
    }
    __builtin_amdgcn_s_setprio(1);
#pragma unroll
    for (int i = 0; i < 4; ++i)
#pragma unroll
      for (int j = 0; j < 4; ++j)
        acc[MH * 4 + i][j] = __builtin_amdgcn_mfma_f32_16x16x32_bf16(
            a[i], bfv[S][j], acc[MH * 4 + i][j], 0, 0, 0);
    __builtin_amdgcn_s_setprio(0);
  };

  // ---- prologue: tile 0 -> buf 0, issue order As0,Bs0,As1,Bs1 ----
  stageA(0, 0, 0); stageB(0, 0, 0); stageA(0, 1, 0); stageB(0, 1, 0);

  const int NT = K >> 6;
  int buf = 0;
  for (int t = 0; t < NT - 1; ++t, buf ^= 1) {
    const int kn = (t + 1) << 6;
    stageA(buf ^ 1, 0, kn);
    asm volatile("s_waitcnt vmcnt(6)" ::: "memory");   // retire t.As0,Bs0
    phase(ic<0>{}, ic<0>{}, ic<1>{}, buf);
    stageB(buf ^ 1, 0, kn);
    asm volatile("s_waitcnt vmcnt(4)" ::: "memory");   // retire t.As1,Bs1
    phase(ic<0>{}, ic<1>{}, ic<1>{}, buf);
    stageA(buf ^ 1, 1, kn);
    phase(ic<1>{}, ic<0>{}, ic<0>{}, buf);
    stageB(buf ^ 1, 1, kn);
    phase(ic<1>{}, ic<1>{}, ic<0>{}, buf);
  }
  // ---- tail tile (no prefetch) ----
  asm volatile("s_waitcnt vmcnt(4)" ::: "memory");
  phase(ic<0>{}, ic<0>{}, ic<1>{}, buf);
  asm volatile("s_waitcnt vmcnt(0)" ::: "memory");
  phase(ic<0>{}, ic<1>{}, ic<1>{}, buf);
  phase(ic<1>{}, ic<0>{}, ic<0>{}, buf);
  phase(ic<1>{}, ic<1>{}, ic<0>{}, buf);

  // ---- epilogue: C/D frag row = q*4 + reg, col = lane&15 (verified) ----
  const int rowb = m0 + wm * 128 + q * 4;
  const int colb = n0 + wn * 64 + ml;
#pragma unroll
  for (int mf = 0; mf < 8; ++mf)
#pragma unroll
    for (int nf = 0; nf < 4; ++nf)
#pragma unroll
      for (int r = 0; r < 4; ++r) {
        size_t idx = (size_t)(rowb + mf * 16 + r) * N + (colb + nf * 16);
        float val = acc[mf][nf][r];
        if (OUT_BF16) ((u16*)Cout)[idx] = f2bf(val);
        else          ((float*)Cout)[idx] = val;
      }
}

// ---------- analytic Gaussian attention: 13-tap conv along L ----------
__global__ __launch_bounds__(256)
void gauss_conv(const u16* __restrict__ v, u16* __restrict__ att, int L) {
  constexpr float wt[13] = {
    1.5229979744712628e-08f, 3.7266531720786709e-06f, 3.3546262790251185e-04f,
    1.1108996538242306e-02f, 1.3533528323661270e-01f, 6.0653065971263342e-01f,
    1.0f,
    6.0653065971263342e-01f, 1.3533528323661270e-01f, 1.1108996538242306e-02f,
    3.3546262790251185e-04f, 3.7266531720786709e-06f, 1.5229979744712628e-08f
  };
  const int t  = threadIdx.x;
  const int fg = t & 15;
  const int li = t >> 4;
  const int l  = blockIdx.x * 16 + li;
  const int h  = blockIdx.y;             // head: block-uniform
  const int b  = blockIdx.z;
  int c;
  switch (h) {
    case 0: case 5: c = l;     break;
    case 1: case 6: c = l - 1; break;
    case 2: case 7: c = l + 1; break;
    case 3:         c = 0;     break;
    default:        c = L - 1; break;
  }
  const int fbase = h * 128 + fg * 8;
  const u16* vb = v + (size_t)b * L * 1024 + fbase;

  float a[8] = {};
  float Z = 0.f;
#pragma unroll
  for (int d = -6; d <= 6; ++d) {
    int idx = c + d;
    bool ok = (idx >= 0) && (idx < L);
    int ic_ = idx < 0 ? 0 : (idx >= L ? L - 1 : idx);
    float w = ok ? wt[d + 6] : 0.f;
    Z += w;
    uint4 p = *reinterpret_cast<const uint4*>(vb + (size_t)ic_ * 1024);
    a[0] = fmaf(w, bf2f((u16)(p.x & 0xffffu)), a[0]);
    a[1] = fmaf(w, bf2f((u16)(p.x >> 16)),     a[1]);
    a[2] = fmaf(w, bf2f((u16)(p.y & 0xffffu)), a[2]);
    a[3] = fmaf(w, bf2f((u16)(p.y >> 16)),     a[3]);
    a[4] = fmaf(w, bf2f((u16)(p.z & 0xffffu)), a[4]);
    a[5] = fmaf(w, bf2f((u16)(p.z >> 16)),     a[5]);
    a[6] = fmaf(w, bf2f((u16)(p.w & 0xffffu)), a[6]);
    a[7] = fmaf(w, bf2f((u16)(p.w >> 16)),     a[7]);
  }
  float inv = 1.0f / Z;
  uint4 o;
  o.x = (u32)f2bf(a[0] * inv) | ((u32)f2bf(a[1] * inv) << 16);
  o.y = (u32)f2bf(a[2] * inv) | ((u32)f2bf(a[3] * inv) << 16);
  o.z = (u32)f2bf(a[4] * inv) | ((u32)f2bf(a[5] * inv) << 16);
  o.w = (u32)f2bf(a[6] * inv) | ((u32)f2bf(a[7] * inv) << 16);
  *reinterpret_cast<uint4*>(att + (size_t)(b * L + l) * 1024 + fbase) = o;
}

// ---------- launch ----------
extern "C" void kernel_launch(void* const* d_in, const int* in_sizes, int n_in,
                              void* d_out, int out_size, void* d_ws, size_t ws_size,
                              hipStream_t stream) {
  const int Bb = 8, L = 2048, E = 1024;
  const int M = Bb * L, N = E, K = E;

  const float* x  = (const float*)d_in[0];
  const float* Wi = (const float*)d_in[1];
  const float* Wo = (const float*)d_in[2];
  float* out = (float*)d_out;

  // ws layout (bf16): [xb 32Mi | v 32Mi | wib 2Mi | wob 2Mi]; att reuses xb
  size_t offV  = (size_t)M * E * 2;
  size_t offWi = offV + (size_t)M * E * 2;
  size_t offWo = offWi + (size_t)E * E * 2;
  size_t need  = offWo + (size_t)E * E * 2;
  if (ws_size < need) return;

  u16* xb  = (u16*)d_ws;
  u16* v   = (u16*)((char*)d_ws + offV);
  u16* wib = (u16*)((char*)d_ws + offWi);
  u16* wob = (u16*)((char*)d_ws + offWo);
  u16* att = xb;  // reuse: conv runs after GEMM1 completes

  int n4x = M * E / 4, n4w = E * E / 4;
  int nblk = (n4x + 2 * n4w) / 256;
  cvt_all<<<nblk, 256, 0, stream>>>((const float4*)x, (uint2*)xb, n4x,
                                    (const float4*)Wi, (uint2*)wib,
                                    (const float4*)Wo, (uint2*)wob, n4w);

  dim3 gg(N / 256, M / 256);   // (4, 64) -> 256 blocks, 1 per CU
  gemm_nt_256<true ><<<gg, 512, 0, stream>>>(xb,  wib, v,   M, N, K);
  gauss_conv<<<dim3(L / 16, 8, Bb), 256, 0, stream>>>(v, att, L);
  gemm_nt_256<false><<<gg, 512, 0, stream>>>(att, wob, out, M, N, K);
}

// Round 2
// 207.291 us; speedup vs baseline: 1.0273x; 1.0162x over previous
//
#include <hip/hip_runtime.h>
#include <stdint.h>

typedef unsigned short u16;
typedef unsigned int   u32;

typedef float  f32x4  __attribute__((ext_vector_type(4)));
typedef __bf16 bf16x8 __attribute__((ext_vector_type(8)));

// ---------- helpers ----------
__device__ __forceinline__ u16 f2bf(float f) {
  union { float f; u32 u; } c; c.f = f;
  u32 u = c.u + 0x7fffu + ((c.u >> 16) & 1u);   // RNE; inputs finite
  return (u16)(u >> 16);
}
__device__ __forceinline__ float bf2f(u16 h) {
  union { u32 u; float f; } c; c.u = ((u32)h) << 16;
  return c.f;
}
__device__ __forceinline__ void gll16(const void* g, void* l) {
  __builtin_amdgcn_global_load_lds(
      (const __attribute__((address_space(1))) void*)g,
      (__attribute__((address_space(3))) void*)l, 16, 0, 0);
}

// ---------- fused fp32 -> bf16 convert: x, Wi, Wo in ONE dispatch ----------
__global__ __launch_bounds__(256)
void cvt_all(const float4* __restrict__ x,  uint2* __restrict__ xb,  int n4x,
             const float4* __restrict__ wi, uint2* __restrict__ wib,
             const float4* __restrict__ wo, uint2* __restrict__ wob, int n4w) {
  int i = blockIdx.x * 256 + threadIdx.x;
  const float4* s; uint2* d; int j;
  if (i < n4x)            { s = x;  d = xb;  j = i; }
  else if (i < n4x + n4w) { s = wi; d = wib; j = i - n4x; }
  else                    { s = wo; d = wob; j = i - n4x - n4w; }
  float4 v = s[j];
  uint2 o;
  o.x = (u32)f2bf(v.x) | ((u32)f2bf(v.y) << 16);
  o.y = (u32)f2bf(v.z) | ((u32)f2bf(v.w) << 16);
  d[j] = o;
}

// ---------- bf16 NT GEMM, 256x256 tile, pipelined window schedule ---------
// C[M,N] = A[M,K] * B[N,K]^T. 512 thr = 8 waves (2M x 4N), per-wave 128x64.
// LDS 128 KiB = 2 buffers x [A-h0 | A-h1 | B-h0 | B-h1], each block
// [128 rows][64 k] bf16 (128 B rows, m201 geometry). Swizzle = m201 st_16x32
// clone: stored chunk p = (s*4+q) ^ ((row>>2 & 1)<<1); applied as inverse
// pre-swizzle on the GLOBAL source so global_load_lds dest stays lane-linear.
// Window anatomy (4 windows per K-tile): [MFMA(p); ds_reads(p+1); gll-stage;
// (vmcnt); sched_barrier; s_barrier]. Reads issued one window ahead of use.
// Region-rotated double buffer: tile t+2's B staged at w1(t) (B-region of
// buf(t) dead after w0(t)), A staged at w3(t) (A-region dead after w2(t)).
// vmcnt(4) at w2 retires tile t+1's 8 loads, keeps t+2's B in flight; no
// full drain in steady state. Every gll issue >=1 barrier after the target
// region's last ds_read sample -> landing can never clobber live data.
template <bool OUT_BF16>
__global__ __launch_bounds__(512, 2)
void gemm_nt_256(const u16* __restrict__ A, const u16* __restrict__ B,
                 void* __restrict__ Cout, int M, int N, int K) {
  __shared__ u16 Ls[65536];                       // 128 KiB
  const int tid  = threadIdx.x;
  const int lane = tid & 63;
  const int wave = tid >> 6;                      // 0..7
  const int wm   = wave >> 2;                     // 0..1
  const int wn   = wave & 3;                      // 0..3
  const int ml   = lane & 15;
  const int q    = lane >> 4;                     // 0..3
  const int qs   = q ^ (((ml >> 2) & 1) << 1);    // swizzled chunk low bits

  // ---- XCD-locality swizzle (bijection; gridDim.x == 4, gridDim.y % 8 == 0)
  const int flat = blockIdx.y * 4 + blockIdx.x;
  const int xcd  = flat & 7;
  const int slot = flat >> 3;
  const int mt   = xcd * (gridDim.y >> 3) + (slot >> 2);
  const int nt   = slot & 3;
  const int m0   = mt * 256;
  const int n0   = nt * 256;

  // ---- staging constants: thread t stages LDS (row srr(+64), chunk tid&7);
  // inverse swizzle on global chunk so the read-side swizzle recovers c.
  const int srr = tid >> 3;                       // 0..63
  const int gc  = (tid & 7) ^ (((tid >> 5) & 1) << 1);
  const u16* Agb = A + (size_t)(m0 + srr) * K + gc * 8;
  const u16* Bgb = B + (size_t)(n0 + srr) * K + gc * 8;
  char* LsB = (char*)Ls;
  const int wlds = wave * 1024;

  auto stageA = [&](int bufb, int h, int k0) {    // 2 x gll16
    char* d = LsB + bufb + h * 16384 + wlds;
    gll16(Agb + (size_t)(h * 128) * K + k0, d);
    gll16(Agb + (size_t)(h * 128 + 64) * K + k0, d + 8192);
  };
  auto stageB = [&](int bufb, int h, int k0) {
    char* d = LsB + bufb + 32768 + h * 16384 + wlds;
    gll16(Bgb + (size_t)(h * 128) * K + k0, d);
    gll16(Bgb + (size_t)(h * 128 + 64) * K + k0, d + 8192);
  };

  // ---- fragment read bases (u16 index within Ls) ----
  const int aB_ = wm * 8192 + ml * 64 + qs * 8;   // +buf*32768 +MH*4096 +i*1024 +s*32
  const int bB_ = 16384 + (wn >> 1) * 8192 + ((wn & 1) * 64 + ml) * 64 + qs * 8;

  f32x4  acc[8][4] = {};
  bf16x8 fa0[4], fa1[4], B0[4], B1[4];

  auto rdA = [&](bf16x8* dst, int bw, int MH, int s) {
#pragma unroll
    for (int i = 0; i < 4; ++i)
      dst[i] = *reinterpret_cast<const bf16x8*>(&Ls[bw + aB_ + MH * 4096 + i * 1024 + s * 32]);
  };
  auto rdB = [&](bf16x8* dst, int bw, int s) {
#pragma unroll
    for (int j = 0; j < 4; ++j)
      dst[j] = *reinterpret_cast<const bf16x8*>(&Ls[bw + bB_ + j * 1024 + s * 32]);
  };
  auto mfma16 = [&](int mh, const bf16x8* a, const bf16x8* b) {
    __builtin_amdgcn_s_setprio(1);
#pragma unroll
    for (int i = 0; i < 4; ++i)
#pragma unroll
      for (int j = 0; j < 4; ++j)
        acc[mh * 4 + i][j] = __builtin_amdgcn_mfma_f32_16x16x32_bf16(
            a[i], b[j], acc[mh * 4 + i][j], 0, 0, 0);
    __builtin_amdgcn_s_setprio(0);
  };
  auto barrier = [&] {
    __builtin_amdgcn_sched_barrier(0);
    __builtin_amdgcn_s_barrier();
  };

  // ---- prologue: tile0 (all 4 blocks), then tile1 B, tile1 A ----
  stageB(0, 0, 0);      stageB(0, 1, 0);
  stageA(0, 0, 0);      stageA(0, 1, 0);
  stageB(65536, 0, 64); stageB(65536, 1, 64);
  stageA(65536, 0, 64); stageA(65536, 1, 64);
  asm volatile("s_waitcnt vmcnt(8)" ::: "memory");  // retire tile0's 8
  barrier();
  rdA(fa0, 0, 0, 0);
  rdB(B0, 0, 0);

  const int NT = K >> 6;                           // 16
  int bufb = 0;
  for (int t = 0; t < NT; ++t, bufb ^= 65536) {
    const int  bw     = bufb >> 1;                 // u16 base, current buffer
    const int  bwn    = (bufb ^ 65536) >> 1;       // u16 base, next buffer
    const bool rdnext = (t + 1 < NT);
    const bool stg    = (t + 2 < NT);
    const int  kst    = (t + 2) << 6;
    // w0: MFMA(MH0,s0); read (MH0,s1)+B(s1)
    mfma16(0, fa0, B0);
    rdA(fa1, bw, 0, 1); rdB(B1, bw, 1);
    barrier();
    // w1: MFMA(MH0,s1); read (MH1,s0); stage B(t+2) -> current buf
    mfma16(0, fa1, B1);
    rdA(fa0, bw, 1, 0);
    if (stg) { stageB(bufb, 0, kst); stageB(bufb, 1, kst); }
    barrier();
    // w2: MFMA(MH1,s0); read (MH1,s1); vmcnt certifies tile t+1
    mfma16(1, fa0, B0);
    rdA(fa1, bw, 1, 1);
    if (stg)         { asm volatile("s_waitcnt vmcnt(4)" ::: "memory"); }
    else if (rdnext) { asm volatile("s_waitcnt vmcnt(0)" ::: "memory"); }
    barrier();
    // w3: MFMA(MH1,s1); read (MH0,s0)+B(s0) of t+1; stage A(t+2)
    mfma16(1, fa1, B1);
    if (rdnext) { rdA(fa0, bwn, 0, 0); rdB(B0, bwn, 0); }
    if (stg) { stageA(bufb, 0, kst); stageA(bufb, 1, kst); }
    barrier();
  }

  // ---- epilogue: C/D frag row = q*4 + reg, col = lane&15 (verified) ----
  const int rowb = m0 + wm * 128 + q * 4;
  const int colb = n0 + wn * 64 + ml;
#pragma unroll
  for (int mf = 0; mf < 8; ++mf)
#pragma unroll
    for (int nf = 0; nf < 4; ++nf)
#pragma unroll
      for (int r = 0; r < 4; ++r) {
        size_t idx = (size_t)(rowb + mf * 16 + r) * N + (colb + nf * 16);
        float val = acc[mf][nf][r];
        if (OUT_BF16) ((u16*)Cout)[idx] = f2bf(val);
        else          ((float*)Cout)[idx] = val;
      }
}

// ---------- analytic Gaussian attention: 13-tap conv along L ----------
__global__ __launch_bounds__(256)
void gauss_conv(const u16* __restrict__ v, u16* __restrict__ att, int L) {
  constexpr float wt[13] = {
    1.5229979744712628e-08f, 3.7266531720786709e-06f, 3.3546262790251185e-04f,
    1.1108996538242306e-02f, 1.3533528323661270e-01f, 6.0653065971263342e-01f,
    1.0f,
    6.0653065971263342e-01f, 1.3533528323661270e-01f, 1.1108996538242306e-02f,
    3.3546262790251185e-04f, 3.7266531720786709e-06f, 1.5229979744712628e-08f
  };
  const int t  = threadIdx.x;
  const int fg = t & 15;
  const int li = t >> 4;
  const int l  = blockIdx.x * 16 + li;
  const int h  = blockIdx.y;             // head: block-uniform
  const int b  = blockIdx.z;
  int c;
  switch (h) {
    case 0: case 5: c = l;     break;
    case 1: case 6: c = l - 1; break;
    case 2: case 7: c = l + 1; break;
    case 3:         c = 0;     break;
    default:        c = L - 1; break;
  }
  const int fbase = h * 128 + fg * 8;
  const u16* vb = v + (size_t)b * L * 1024 + fbase;

  float a[8] = {};
  float Z = 0.f;
#pragma unroll
  for (int d = -6; d <= 6; ++d) {
    int idx = c + d;
    bool ok = (idx >= 0) && (idx < L);
    int ic_ = idx < 0 ? 0 : (idx >= L ? L - 1 : idx);
    float w = ok ? wt[d + 6] : 0.f;
    Z += w;
    uint4 p = *reinterpret_cast<const uint4*>(vb + (size_t)ic_ * 1024);
    a[0] = fmaf(w, bf2f((u16)(p.x & 0xffffu)), a[0]);
    a[1] = fmaf(w, bf2f((u16)(p.x >> 16)),     a[1]);
    a[2] = fmaf(w, bf2f((u16)(p.y & 0xffffu)), a[2]);
    a[3] = fmaf(w, bf2f((u16)(p.y >> 16)),     a[3]);
    a[4] = fmaf(w, bf2f((u16)(p.z & 0xffffu)), a[4]);
    a[5] = fmaf(w, bf2f((u16)(p.z >> 16)),     a[5]);
    a[6] = fmaf(w, bf2f((u16)(p.w & 0xffffu)), a[6]);
    a[7] = fmaf(w, bf2f((u16)(p.w >> 16)),     a[7]);
  }
  float inv = 1.0f / Z;
  uint4 o;
  o.x = (u32)f2bf(a[0] * inv) | ((u32)f2bf(a[1] * inv) << 16);
  o.y = (u32)f2bf(a[2] * inv) | ((u32)f2bf(a[3] * inv) << 16);
  o.z = (u32)f2bf(a[4] * inv) | ((u32)f2bf(a[5] * inv) << 16);
  o.w = (u32)f2bf(a[6] * inv) | ((u32)f2bf(a[7] * inv) << 16);
  *reinterpret_cast<uint4*>(att + (size_t)(b * L + l) * 1024 + fbase) = o;
}

// ---------- launch ----------
extern "C" void kernel_launch(void* const* d_in, const int* in_sizes, int n_in,
                              void* d_out, int out_size, void* d_ws, size_t ws_size,
                              hipStream_t stream) {
  const int Bb = 8, L = 2048, E = 1024;
  const int M = Bb * L, N = E, K = E;

  const float* x  = (const float*)d_in[0];
  const float* Wi = (const float*)d_in[1];
  const float* Wo = (const float*)d_in[2];
  float* out = (float*)d_out;

  // ws layout (bf16): [xb 32Mi | v 32Mi | wib 2Mi | wob 2Mi]; att reuses xb
  size_t offV  = (size_t)M * E * 2;
  size_t offWi = offV + (size_t)M * E * 2;
  size_t offWo = offWi + (size_t)E * E * 2;
  size_t need  = offWo + (size_t)E * E * 2;
  if (ws_size < need) return;

  u16* xb  = (u16*)d_ws;
  u16* v   = (u16*)((char*)d_ws + offV);
  u16* wib = (u16*)((char*)d_ws + offWi);
  u16* wob = (u16*)((char*)d_ws + offWo);
  u16* att = xb;  // reuse: conv runs after GEMM1 completes

  int n4x = M * E / 4, n4w = E * E / 4;
  int nblk = (n4x + 2 * n4w) / 256;
  cvt_all<<<nblk, 256, 0, stream>>>((const float4*)x, (uint2*)xb, n4x,
                                    (const float4*)Wi, (uint2*)wib,
                                    (const float4*)Wo, (uint2*)wob, n4w);

  dim3 gg(N / 256, M / 256);   // (4, 64) -> 256 blocks, 1 per CU
  gemm_nt_256<true ><<<gg, 512, 0, stream>>>(xb,  wib, v,   M, N, K);
  gauss_conv<<<dim3(L / 16, 8, Bb), 256, 0, stream>>>(v, att, L);
  gemm_nt_256<false><<<gg, 512, 0, stream>>>(att, wob, out, M, N, K);
}